// Round 3
// baseline (15994.295 us; speedup 1.0000x reference)
//
#include <hip/hip_runtime.h>

#define NB 36
#define NT 60

// ---------------- one-time prep kernels ----------------

// wt[(cin*9+dd)*Cout + co] = W[(co*Cin+cin)*9 + dd]
template<int Cin,int Cout>
__global__ void k_wt(const float* __restrict__ W, float* __restrict__ wt){
  int i = blockIdx.x*256 + threadIdx.x;
  const int n = Cin*9*Cout;
  if(i>=n) return;
  int co = i % Cout;
  int r  = i / Cout;
  int cin = r/9, dd = r%9;
  wt[i] = W[(co*Cin+cin)*9 + dd];
}

// xb[t][b][c][h][w] = (data[b][c][h][w][t] > 1) ? 1 : 0
__global__ void k_bin(const float* __restrict__ data, float* __restrict__ xb){
  int i = blockIdx.x*256 + threadIdx.x;
  const int n = NT*NB*2*32*32;
  if(i>=n) return;
  int t = i / (NB*2*32*32);
  int r = i % (NB*2*32*32);
  xb[i] = (data[(size_t)r*NT + t] > 1.0f) ? 1.0f : 0.0f;
}

// ---------------- fused conv3x3 + LIAF (+ optional avgpool2 + LIAF) ----------------
// blockDim = (HW, TY). Thread: PX consecutive rows x CO couts at column w.
// Weights staged in LDS (broadcast reads, conflict-free).
// SWZ: all blocks of one batch land on one XCD (bid%8 == b%8) so the input
// re-read across cog-blocks is served by that XCD's L2 instead of L3.
template<int Cin,int Cout,int HW,int CO,int PX,int TY,bool POOL,bool SWZ>
__global__ void __launch_bounds__(HW*TY)
k_conv(const float* __restrict__ x, const float* __restrict__ wt,
       const float* __restrict__ bias, float* __restrict__ dm,
       float* __restrict__ out, float* __restrict__ dmp, float* __restrict__ outp)
{
  const int NCOG = Cout/CO;
  const int TH   = PX*TY;
  const int NHG  = HW/TH;
  const int NH4  = CO/4;
  const int NBI  = NCOG*NHG;
  int bid = blockIdx.x;
  int cog, hg, b;
  if(SWZ){
    int b_lo = bid & 7; int r = bid >> 3;
    int inner = r % NBI; int b_hi = r / NBI;
    b = b_hi*8 + b_lo;
    if(b >= NB) return;           // uniform per block
    cog = inner / NHG; hg = inner % NHG;
  } else {
    cog = bid % NCOG; hg = (bid/NCOG) % NHG; b = bid/(NCOG*NHG);
  }
  int w  = threadIdx.x;
  int ty = threadIdx.y;
  int h0 = hg*TH + ty*PX;

  __shared__ __align__(16) float wl[Cin*9*CO];
  const int NTH = HW*TY;
  int tid = ty*HW + w;
  for(int j=tid; j<Cin*9*CO; j+=NTH){
    int c  = j % CO;
    int rr = j / CO;
    wl[j] = wt[rr*Cout + cog*CO + c];
  }
  __syncthreads();

  float accs[PX][CO];
  #pragma unroll
  for(int p=0;p<PX;p++)
    #pragma unroll
    for(int c=0;c<CO;c++) accs[p][c]=0.f;

  for(int cin=0; cin<Cin; cin++){
    const float* xc = x + ((size_t)b*Cin + cin)*HW*HW;
    float xmv[PX+2], x0v[PX+2], xpv[PX+2];
    #pragma unroll
    for(int r=0;r<PX+2;r++){
      int hh = h0 - 1 + r;
      bool hv = (hh>=0) && (hh<HW);
      const float* xr = xc + hh*HW;
      x0v[r] =  hv            ? xr[w]   : 0.f;
      xmv[r] = (hv && w>0)    ? xr[w-1] : 0.f;
      xpv[r] = (hv && w<HW-1) ? xr[w+1] : 0.f;
    }
    const float4* w4 = (const float4*)(wl + cin*9*CO);
    #pragma unroll
    for(int dh=0;dh<3;dh++){
      float4 wa[NH4], wb[NH4], wc[NH4];
      #pragma unroll
      for(int g=0;g<NH4;g++){
        wa[g] = w4[(dh*3+0)*NH4+g];
        wb[g] = w4[(dh*3+1)*NH4+g];
        wc[g] = w4[(dh*3+2)*NH4+g];
      }
      #pragma unroll
      for(int g=0;g<NH4;g++){
        const float* A  = (const float*)&wa[g];
        const float* Bp = (const float*)&wb[g];
        const float* Cp = (const float*)&wc[g];
        #pragma unroll
        for(int cc=0;cc<4;cc++){
          #pragma unroll
          for(int px=0;px<PX;px++){
            int r = dh+px;
            accs[px][g*4+cc] += A[cc]*xmv[r] + Bp[cc]*x0v[r] + Cp[cc]*xpv[r];
          }
        }
      }
    }
  }

  int co0 = cog*CO;
  size_t cb = (size_t)b*Cout;
  #pragma unroll
  for(int co=0; co<CO; co++){
    float bsv = bias[co0+co];
    float vs[PX/2 > 0 ? PX/2 : 1];
    #pragma unroll
    for(int pr=0;pr<PX/2;pr++) vs[pr]=0.f;
    #pragma unroll
    for(int px=0; px<PX; px++){
      size_t idx = (cb + co0 + co)*HW*HW + (size_t)(h0+px)*HW + w;
      float mem = dm[idx] + accs[px][co] + bsv;
      float o = mem > 0.f ? mem : 0.f;
      dm[idx] = (mem > 0.5f) ? 0.f : 0.3f*mem;
      if(POOL) vs[px>>1] += o;
      else     out[idx] = o;
    }
    if(POOL){
      #pragma unroll
      for(int pr=0; pr<PX/2; pr++){
        float s = vs[pr];
        s += __shfl_xor(s, 1, 64);
        if((w&1)==0){
          int ph = (h0>>1)+pr, pw = w>>1;
          size_t pidx = (cb + co0 + co)*(HW/2)*(HW/2) + (size_t)ph*(HW/2) + pw;
          float pm = dmp[pidx] + s*0.25f;
          outp[pidx] = pm > 0.f ? pm : 0.f;
          dmp[pidx]  = (pm > 0.5f) ? 0.f : 0.3f*pm;
        }
      }
    }
  }
}

// ---------------- FC1 partial GEMM: C[36,256] += X[36,8192] . Wf1[256,8192]^T ----------------
// grid = 16 k-splits x 8 o-tiles = 128 blocks, 256 threads (4 waves).
// Each wave covers the 32o x 40b tile over its k-quarter of each 64-k chunk;
// writes its own partial slice (64 slices total, deterministic, no atomics).
// LDS rows padded to 68 floats: broadcast-group reads hit distinct banks.
__global__ void __launch_bounds__(256)
k_fc1_part(const float* __restrict__ X, const float* __restrict__ Wf,
           float* __restrict__ u1s){
  const int tid = threadIdx.x;
  int ot = blockIdx.x & 7;
  int ks = blockIdx.x >> 3;
  int o0 = ot*32;
  int k0 = ks*512;
  __shared__ __align__(16) float Wl[32*68];
  __shared__ __align__(16) float Xl[40*68];
  int w_id = tid >> 6, lane = tid & 63;
  int o_l = lane & 7, bg = lane >> 3;
  float acc[4][5];
  #pragma unroll
  for(int i=0;i<4;i++)
    #pragma unroll
    for(int j=0;j<5;j++) acc[i][j]=0.f;

  for(int c=0; c<8; c++){
    int kb = k0 + c*64;
    for(int idx=tid; idx<512; idx+=256){
      int r = idx >> 4, j = idx & 15;
      *(float4*)&Wl[r*68 + j*4] = *(const float4*)&Wf[(size_t)(o0+r)*8192 + kb + j*4];
    }
    for(int idx=tid; idx<640; idx+=256){
      int r = idx >> 4, j = idx & 15;
      float4 v = make_float4(0.f,0.f,0.f,0.f);
      if(r < 36) v = *(const float4*)&X[(size_t)r*8192 + kb + j*4];
      *(float4*)&Xl[r*68 + j*4] = v;
    }
    __syncthreads();
    #pragma unroll
    for(int c4=0; c4<4; c4++){
      int g = w_id*4 + c4;          // float4 group within chunk, wave-partitioned
      float4 wv[4], xv[5];
      #pragma unroll
      for(int oi=0;oi<4;oi++) wv[oi] = *(const float4*)&Wl[(o_l+8*oi)*68 + g*4];
      #pragma unroll
      for(int bi=0;bi<5;bi++) xv[bi] = *(const float4*)&Xl[(bg*5+bi)*68 + g*4];
      #pragma unroll
      for(int oi=0;oi<4;oi++)
        #pragma unroll
        for(int bi=0;bi<5;bi++)
          acc[oi][bi] += wv[oi].x*xv[bi].x + wv[oi].y*xv[bi].y
                       + wv[oi].z*xv[bi].z + wv[oi].w*xv[bi].w;
    }
    __syncthreads();
  }
  int slice = ks*4 + w_id;          // 64 slices
  #pragma unroll
  for(int bi=0;bi<5;bi++){
    int b = bg*5 + bi;
    if(b < NB){
      #pragma unroll
      for(int oi=0;oi<4;oi++)
        u1s[((size_t)slice*NB + b)*256 + o0 + o_l + 8*oi] = acc[oi][bi];
    }
  }
}

// ---------------- fused FC1-reduce + LIAF + FC(256->11) + LIAF + accumulate ----------------
// grid = 36 blocks, 64 threads. Phase 1: sum 64 partial slices, LIAF (h1).
// Phase 2: 11-way dot via shuffle-reduce, LIAF (h2), accumulate /60.
__global__ void k_fc2_liaf(const float* __restrict__ u1s, const float* __restrict__ bf1,
                           const float* __restrict__ Wf2, const float* __restrict__ bf2,
                           float* __restrict__ dmh1, float* __restrict__ dmh2,
                           float* __restrict__ acc){
  int b = blockIdx.x;
  int lane = threadIdx.x;
  float xv[4];
  #pragma unroll
  for(int j=0;j<4;j++){
    int o = lane + 64*j;
    float u = bf1[o];
    const float* p = u1s + (size_t)b*256 + o;
    for(int s=0;s<64;s++) u += p[(size_t)s*NB*256];
    int idx = b*256 + o;
    float mem = dmh1[idx] + u;
    xv[j] = mem > 0.f ? mem : 0.f;
    dmh1[idx] = (mem > 0.5f) ? 0.f : 0.3f*mem;
  }
  for(int o=0;o<11;o++){
    const float* wr = Wf2 + o*256;
    float s = xv[0]*wr[lane] + xv[1]*wr[lane+64] + xv[2]*wr[lane+128] + xv[3]*wr[lane+192];
    #pragma unroll
    for(int off=32; off>0; off>>=1) s += __shfl_down(s, off, 64);
    if(lane==0){
      int idx = b*11 + o;
      float mem = dmh2[idx] + s + bf2[o];
      float outv = mem > 0.f ? mem : 0.f;
      dmh2[idx] = (mem > 0.5f) ? 0.f : 0.3f*mem;
      acc[idx] += outv * (1.0f/60.0f);
    }
  }
}

// ---------------- launch ----------------

extern "C" void kernel_launch(void* const* d_in, const int* in_sizes, int n_in,
                              void* d_out, int out_size, void* d_ws, size_t ws_size,
                              hipStream_t stream) {
  const float* data = (const float*)d_in[0];
  const float* W0  = (const float*)d_in[2];  const float* b0  = (const float*)d_in[3];
  const float* W1  = (const float*)d_in[4];  const float* b1  = (const float*)d_in[5];
  const float* W2  = (const float*)d_in[6];  const float* b2  = (const float*)d_in[7];
  const float* Wf1 = (const float*)d_in[8];  const float* bf1 = (const float*)d_in[9];
  const float* Wf2 = (const float*)d_in[10]; const float* bf2 = (const float*)d_in[11];

  float* ws = (float*)d_ws;
  const size_t S_XB   = (size_t)NT*NB*2*32*32;
  const size_t S_W0T  = 2*9*64;
  const size_t S_W1T  = 64*9*128;
  const size_t S_W2T  = 128*9*128;
  const size_t S_OUT0 = (size_t)NB*64*32*32;
  const size_t S_DM1  = (size_t)NB*128*32*32;
  const size_t S_OP1  = (size_t)NB*128*16*16;
  const size_t S_OP2  = (size_t)NB*128*8*8;
  const size_t S_OH1  = (size_t)NB*256;
  const size_t S_U1S  = (size_t)64*NB*256;

  float* xb    = ws;  ws += S_XB;
  float* w0t   = ws;  ws += S_W0T;
  float* w1t   = ws;  ws += S_W1T;
  float* w2t   = ws;  ws += S_W2T;
  float* out0  = ws;  ws += S_OUT0;
  float* outp1 = ws;  ws += S_OP1;
  float* outp2 = ws;  ws += S_OP2;
  float* u1s   = ws;  ws += S_U1S;
  float* dm0   = ws;  ws += S_OUT0;
  float* dm1   = ws;  ws += S_DM1;
  float* dmp1  = ws;  ws += S_OP1;
  float* dm2   = ws;  ws += S_OP1;
  float* dmp2  = ws;  ws += S_OP2;
  float* dmh1  = ws;  ws += S_OH1;
  float* dmh2  = ws;  ws += (size_t)NB*11;

  const size_t dm_floats = S_OUT0 + S_DM1 + S_OP1 + S_OP1 + S_OP2 + S_OH1 + (size_t)NB*11;
  hipMemsetAsync(dm0, 0, dm_floats*sizeof(float), stream);
  hipMemsetAsync(d_out, 0, (size_t)NB*11*sizeof(float), stream);

  k_bin<<<dim3((S_XB+255)/256), dim3(256), 0, stream>>>(data, xb);
  k_wt<2,64>   <<<dim3((S_W0T+255)/256), dim3(256), 0, stream>>>(W0, w0t);
  k_wt<64,128> <<<dim3((S_W1T+255)/256), dim3(256), 0, stream>>>(W1, w1t);
  k_wt<128,128><<<dim3((S_W2T+255)/256), dim3(256), 0, stream>>>(W2, w2t);

  for(int t=0; t<NT; t++){
    const float* xt = xb + (size_t)t*NB*2*32*32;
    // conv0: 2->64 @32x32, CO=8, PX=2, TY=8, no swizzle -> 576 blocks of 256
    k_conv<2,64,32,8,2,8,false,false><<<dim3(36*8*2), dim3(32,8), 0, stream>>>(
        xt, w0t, b0, dm0, out0, nullptr, nullptr);
    // conv1+pool1: 64->128 @32x32, CO=8, PX=2, TY=8, XCD-swizzled -> 40*32=1280 blocks
    k_conv<64,128,32,8,2,8,true,true><<<dim3(40*32), dim3(32,8), 0, stream>>>(
        out0, w1t, b1, dm1, nullptr, dmp1, outp1);
    // conv2+pool2: 128->128 @16x16, CO=4, PX=2, TY=8, XCD-swizzled -> 1280 blocks of 128
    k_conv<128,128,16,4,2,8,true,true><<<dim3(40*32), dim3(16,8), 0, stream>>>(
        outp1, w2t, b2, dm2, nullptr, dmp2, outp2);
    // fc1 split-K partial GEMM
    k_fc1_part<<<dim3(128), dim3(256), 0, stream>>>(outp2, Wf1, u1s);
    // fc1-reduce + LIAF + fc2 + LIAF + accumulate
    k_fc2_liaf<<<dim3(36), dim3(64), 0, stream>>>(u1s, bf1, Wf2, bf2, dmh1, dmh2, (float*)d_out);
  }
}